// Round 11
// baseline (236.829 us; speedup 1.0000x reference)
//
#include <hip/hip_runtime.h>
#include <hip/hip_bf16.h>
#include <stdint.h>

// ---------------------------------------------------------------------------
// BondPoolingLayer: out[e] = MLP(cat(h[src],h[dst])) + MLP(cat(h[dst],h[src]))
// MLP: 256 ->(W1,b1,relu) 128 ->(W2,b2,relu) 128 ->(W3,b3) 2
//
// R16 = R15 fused kernel + LDS TIME-SHARING for 2 blocks/CU.
//  - R15 counters: 108us, Occ 19% (133KB LDS => 1 block/CU = 8 waves),
//    MfmaUtil 16 / VALU 20 / HBM 13% — occupancy wall, not roofline.
//    Standalone edge pushed the same gather stream at 1.7 TB/s; fused runs
//    it at 1.0 because the serial compute tail idles the memory system.
//  - Fix: ONE 64KB region. Phase 1: W1s (128x256). After barrier #2 (all
//    L1 reads done): lower 32KB restaged as W2s (from L2-hot W2t), upper
//    32KB becomes the bounce scratch. Biases/W3 from global in epilogues
//    (R5/R9-proven). LDS 133->64KB => 2 blocks/CU = 16 waves.
//  - Regs: straight-line (never spilled this session), peak ~116 designed;
//    cap (512,4) = 128. Both R15 pass-fusions kept.
//  - Barriers: #1 W1s ready; #2 W1s reads done (union safe); #3 W2s ready.
//    The bounce + W2s global loads overlap between #2 and #3.
// ---------------------------------------------------------------------------

typedef __attribute__((ext_vector_type(8))) short bf16x8;
typedef __attribute__((ext_vector_type(4))) float f32x4;

__device__ __forceinline__ float bf2f(unsigned u16) {
    union { unsigned u; float f; } v; v.u = u16 << 16;
    return v.f;
}
__device__ __forceinline__ unsigned short f2bf(float f) {
    union { float f; unsigned u; } v; v.f = f;
    unsigned u = v.u;
    unsigned r = u + 0x7FFFu + ((u >> 16) & 1u);   // RNE
    return (unsigned short)(r >> 16);
}

// swizzles: rows of 128 bf16 (16 chunks) and 256 bf16 (32 chunks); chunk=16B.
__device__ __forceinline__ int swz(int f, int c) {       // row len 128
    return f * 128 + ((c ^ (f & 7)) << 3);
}
__device__ __forceinline__ int swzA(int f, int c) {      // row len 256
    return f * 256 + ((c ^ (f & 7)) << 3);
}

// two float4 (8 consecutive fp32) -> bf16x8 fragment (packed RNE)
__device__ __forceinline__ bf16x8 cvt8v(float4 x, float4 y) {
    union { bf16x8 v; __hip_bfloat162 h[4]; } R;
    R.h[0] = __float22bfloat162_rn(float2{x.x, x.y});
    R.h[1] = __float22bfloat162_rn(float2{x.z, x.w});
    R.h[2] = __float22bfloat162_rn(float2{y.x, y.y});
    R.h[3] = __float22bfloat162_rn(float2{y.z, y.w});
    return R.v;
}

#define MFMA(a, b, c) __builtin_amdgcn_mfma_f32_16x16x32_bf16((a), (b), (c), 0, 0, 0)

// ---------------------------------------------------------------------------
// Kernel 0: weight prep.
// W1c[j][k] (j in [0,128) out-feature, k in [0,256) concat-input) = W1[k][j]
// W2t[n][k] = W2[k][n]
// ---------------------------------------------------------------------------
__global__ void prep_weights(const float* __restrict__ W1,
                             const float* __restrict__ W2,
                             unsigned short* __restrict__ W1c,
                             unsigned short* __restrict__ W2t) {
    int idx = blockIdx.x * 256 + threadIdx.x;
    if (idx < 128 * 256) {
        int j = idx >> 8, k = idx & 255;
        W1c[idx] = f2bf(W1[k * 128 + j]);
    } else {
        int i2 = idx - 128 * 256;
        if (i2 < 128 * 128) {
            int n = i2 >> 7, k = i2 & 127;
            W2t[i2] = f2bf(W2[k * 128 + n]);
        }
    }
}

// ---------------------------------------------------------------------------
// Fused per-edge kernel. Block = 512 thr = 8 waves = 128 edges.
// Wave = 16 edges (lane ml owns edge wv*16+ml; quad = k/feature part).
// LDS: one 64KB region, time-shared (W1s -> W2s + scr).
// ---------------------------------------------------------------------------
__global__ __launch_bounds__(512, 4) void edge_fused(
    const float* __restrict__ h, const int* __restrict__ src,
    const int* __restrict__ dst, const unsigned short* __restrict__ W1c,
    const unsigned short* __restrict__ W2t, const float* __restrict__ b1,
    const float* __restrict__ b2, const float* __restrict__ W3,
    const float* __restrict__ b3, float* __restrict__ out, int E) {
    __shared__ unsigned short region[128 * 256];   // 64KB union

    int t = threadIdx.x;
    int lane = t & 63;
    int wv = t >> 6;
    int ml = lane & 15, quad = lane >> 4;

    // ---- phase 1 staging: W1s fills the whole region ----
    {
        int r = t >> 2, q = t & 3;
        const uint4* s = (const uint4*)(W1c + (size_t)r * 256 + q * 64);
#pragma unroll
        for (int i = 0; i < 8; ++i)
            *(uint4*)(region + swzA(r, q * 8 + i)) = s[i];
    }

    // ---- batch h gathers (16 x 16B fp32 loads) BEFORE the barrier ----
    int e = blockIdx.x * 128 + wv * 16 + ml;
    int ec = (e < E) ? e : (E - 1);
    int si = src[ec], di = dst[ec];
    const float* hs = h + (size_t)si * 128;
    const float* hd = h + (size_t)di * 128;

    float4 s0a, s0b, s1a, s1b, s2a, s2b, s3a, s3b;
    float4 d0a, d0b, d1a, d1b, d2a, d2b, d3a, d3b;
    {
        int ko = quad * 8;
        s0a = *(const float4*)(hs + ko);       s0b = *(const float4*)(hs + ko + 4);
        s1a = *(const float4*)(hs + 32 + ko);  s1b = *(const float4*)(hs + 36 + ko);
        s2a = *(const float4*)(hs + 64 + ko);  s2b = *(const float4*)(hs + 68 + ko);
        s3a = *(const float4*)(hs + 96 + ko);  s3b = *(const float4*)(hs + 100 + ko);
        d0a = *(const float4*)(hd + ko);       d0b = *(const float4*)(hd + ko + 4);
        d1a = *(const float4*)(hd + 32 + ko);  d1b = *(const float4*)(hd + 36 + ko);
        d2a = *(const float4*)(hd + 64 + ko);  d2b = *(const float4*)(hd + 68 + ko);
        d3a = *(const float4*)(hd + 96 + ko);  d3b = *(const float4*)(hd + 100 + ko);
    }
    // convert: lane (ml,quad) holds h[own edge][k = kk*32 + quad*8 .. +8]
    bf16x8 hsf[4], hdf[4];
    hsf[0] = cvt8v(s0a, s0b); hsf[1] = cvt8v(s1a, s1b);
    hsf[2] = cvt8v(s2a, s2b); hsf[3] = cvt8v(s3a, s3b);
    hdf[0] = cvt8v(d0a, d0b); hdf[1] = cvt8v(d1a, d1b);
    hdf[2] = cvt8v(d2a, d2b); hdf[3] = cvt8v(d3a, d3b);

    __syncthreads();   // barrier 1: W1s ready

    // ========== layer 1, FUSED fwd+rev: each W1s fragment read ONCE ========
    f32x4 accf[8] = {}, accr[8] = {};
#pragma unroll
    for (int kk = 0; kk < 4; ++kk) {     // k 0..127: fwd<-hs, rev<-hd
#pragma unroll
        for (int ct = 0; ct < 8; ++ct) {
            bf16x8 a = *(const bf16x8*)(region + swzA(ct * 16 + ml, kk * 4 + quad));
            accf[ct] = MFMA(a, hsf[kk], accf[ct]);
            accr[ct] = MFMA(a, hdf[kk], accr[ct]);
        }
    }
#pragma unroll
    for (int kk = 4; kk < 8; ++kk) {     // k 128..255: fwd<-hd, rev<-hs
#pragma unroll
        for (int ct = 0; ct < 8; ++ct) {
            bf16x8 a = *(const bf16x8*)(region + swzA(ct * 16 + ml, kk * 4 + quad));
            accf[ct] = MFMA(a, hdf[kk - 4], accf[ct]);
            accr[ct] = MFMA(a, hsf[kk - 4], accr[ct]);
        }
    }

    __syncthreads();   // barrier 2: all waves done READING W1s; union safe

    // ---- phase 2 staging: W2s into lower 32KB (from L2-hot W2t) ----
    {
        int f = t >> 2, q4 = t & 3;
        const uint4* s = (const uint4*)(W2t + (size_t)f * 128 + q4 * 32);
#pragma unroll
        for (int i = 0; i < 4; ++i)
            *(uint4*)(region + swz(f, q4 * 4 + i)) = s[i];
    }

    // ---- bounce (upper 32KB = scr; within-wave only, b1 from global) ----
    unsigned short* scrW = region + 16384 + wv * 2048;   // wave's 16x128 scratch
    bf16x8 afw[4], arv[4];
    {
        // round 1 (fwd)
#pragma unroll
        for (int ct = 0; ct < 8; ++ct) {
            int fb = ct * 16 + quad * 4;
            float4 bv = *(const float4*)(b1 + fb);
            union { uint2 u; __hip_bfloat162 h2[2]; } o;
            o.h2[0] = __float22bfloat162_rn(float2{fmaxf(accf[ct][0] + bv.x, 0.f),
                                                   fmaxf(accf[ct][1] + bv.y, 0.f)});
            o.h2[1] = __float22bfloat162_rn(float2{fmaxf(accf[ct][2] + bv.z, 0.f),
                                                   fmaxf(accf[ct][3] + bv.w, 0.f)});
            int chunk = ct * 2 + (quad >> 1);             // fb>>3
            *(uint2*)(scrW + ml * 128 + ((chunk ^ (ml & 7)) << 3) + ((quad & 1) << 2)) = o.u;
        }
        __threadfence_block();   // within-wave ds_write -> ds_read ordering
#pragma unroll
        for (int kk = 0; kk < 4; ++kk) {
            int chunk = kk * 4 + quad;
            afw[kk] = *(const bf16x8*)(scrW + ml * 128 + ((chunk ^ (ml & 7)) << 3));
        }
        __threadfence_block();   // round-1 reads ordered before round-2 writes

        // round 2 (rev)
#pragma unroll
        for (int ct = 0; ct < 8; ++ct) {
            int fb = ct * 16 + quad * 4;
            float4 bv = *(const float4*)(b1 + fb);
            union { uint2 u; __hip_bfloat162 h2[2]; } o;
            o.h2[0] = __float22bfloat162_rn(float2{fmaxf(accr[ct][0] + bv.x, 0.f),
                                                   fmaxf(accr[ct][1] + bv.y, 0.f)});
            o.h2[1] = __float22bfloat162_rn(float2{fmaxf(accr[ct][2] + bv.z, 0.f),
                                                   fmaxf(accr[ct][3] + bv.w, 0.f)});
            int chunk = ct * 2 + (quad >> 1);
            *(uint2*)(scrW + ml * 128 + ((chunk ^ (ml & 7)) << 3) + ((quad & 1) << 2)) = o.u;
        }
        __threadfence_block();
#pragma unroll
        for (int kk = 0; kk < 4; ++kk) {
            int chunk = kk * 4 + quad;
            arv[kk] = *(const bf16x8*)(scrW + ml * 128 + ((chunk ^ (ml & 7)) << 3));
        }
    }

    __syncthreads();   // barrier 3: W2s staged (bounce overlapped the loads)

    // ========== layer 2+3, FUSED fwd+rev: each W2s fragment read ONCE ======
    float p0[4] = {0.f, 0.f, 0.f, 0.f};
    float p1[4] = {0.f, 0.f, 0.f, 0.f};
    {
        f32x4 acc2f[8] = {}, acc2r[8] = {};
#pragma unroll
        for (int kk = 0; kk < 4; ++kk) {
#pragma unroll
            for (int ct = 0; ct < 8; ++ct) {
                bf16x8 b = *(const bf16x8*)(region + swz(ct * 16 + ml, kk * 4 + quad));
                acc2f[ct] = MFMA(afw[kk], b, acc2f[ct]);
                acc2r[ct] = MFMA(arv[kk], b, acc2r[ct]);
            }
        }
        // epilogue: +b2, relu, dot W3 columns (consts from global, L2-hot)
#pragma unroll
        for (int ct = 0; ct < 8; ++ct) {
            int c = ct * 16 + ml;
            float2 w3 = *(const float2*)(W3 + c * 2);
            float bc = b2[c];
#pragma unroll
            for (int reg = 0; reg < 4; ++reg) {
                float hf = fmaxf(acc2f[ct][reg] + bc, 0.f);
                float hr = fmaxf(acc2r[ct][reg] + bc, 0.f);
                p0[reg] += (hf + hr) * w3.x;
                p1[reg] += (hf + hr) * w3.y;
            }
        }
    }

    // butterfly over the 16 feature lanes
#pragma unroll
    for (int m = 1; m < 16; m <<= 1) {
#pragma unroll
        for (int reg = 0; reg < 4; ++reg) {
            p0[reg] += __shfl_xor(p0[reg], m);
            p1[reg] += __shfl_xor(p1[reg], m);
        }
    }

    // lane ml==0 writes component 0, ml==1 writes component 1
    if (ml < 2) {
        float bb = 2.f * b3[ml];
#pragma unroll
        for (int reg = 0; reg < 4; ++reg) {
            int ee = blockIdx.x * 128 + wv * 16 + quad * 4 + reg;
            if (ee < E) {
                float v = (ml == 0) ? p0[reg] : p1[reg];
                out[(size_t)ee * 2 + ml] = v + bb;
            }
        }
    }
}

// ---------------------------------------------------------------------------
extern "C" void kernel_launch(void* const* d_in, const int* in_sizes, int n_in,
                              void* d_out, int out_size, void* d_ws, size_t ws_size,
                              hipStream_t stream) {
    (void)n_in; (void)out_size; (void)ws_size;
    const float* h  = (const float*)d_in[0];
    const int*   sr = (const int*)d_in[1];
    const int*   ds = (const int*)d_in[2];
    const float* W1 = (const float*)d_in[3];
    const float* b1 = (const float*)d_in[4];
    const float* W2 = (const float*)d_in[5];
    const float* b2 = (const float*)d_in[6];
    const float* W3 = (const float*)d_in[7];
    const float* b3 = (const float*)d_in[8];
    float* out = (float*)d_out;

    int E = in_sizes[1];

    unsigned short* W1c = (unsigned short*)d_ws;          // 128*256
    unsigned short* W2t = W1c + 128 * 256;                // 128*128

    prep_weights<<<(128 * 256 + 128 * 128 + 255) / 256, 256, 0, stream>>>(W1, W2, W1c, W2t);

    int etiles = (E + 127) / 128;
    edge_fused<<<etiles, 512, 0, stream>>>(h, sr, ds, W1c, W2t, b1, b2, W3, b3, out, E);
}

// Round 12
// 228.208 us; speedup vs baseline: 1.0378x; 1.0378x over previous
//
#include <hip/hip_runtime.h>
#include <hip/hip_bf16.h>
#include <stdint.h>

// ---------------------------------------------------------------------------
// BondPoolingLayer: out[e] = MLP(cat(h[src],h[dst])) + MLP(cat(h[dst],h[src]))
// MLP: 256 ->(W1,b1,relu) 128 ->(W2,b2,relu) 128 ->(W3,b3) 2
//
// R17 = R15 verbatim (session best: fused 108us, total 227.2) + s_setprio
//       around the MFMA clusters (T5; low-risk, attn-like wave structure).
//  - R15<->R16 controlled pair PROVED the remaining tension: 2 blocks/CU
//    needs <=128 regs (kills the 16-deep gather window, R16: VGPR 64,
//    gathers serialized + partial spill, 108->126us despite 2x occupancy);
//    full gather window needs ~184 regs incl AGPR -> 1 block/CU. R15 is
//    the better end. Unfusing L1 to cut AGPR doubles W1s reads (R14's
//    conflict wall). Structure-space closed.
//  - Ceiling arithmetic: gather stream ~220MB demand at ~3.3 TB/s mixed
//    L3 ~= 55-65us floor; serial L1/bounce/L2 phases on 8 waves/CU give
//    ~108us. Total = 111us kernels + ~116us harness-fixed.
// ---------------------------------------------------------------------------

typedef __attribute__((ext_vector_type(8))) short bf16x8;
typedef __attribute__((ext_vector_type(4))) float f32x4;

__device__ __forceinline__ float bf2f(unsigned u16) {
    union { unsigned u; float f; } v; v.u = u16 << 16;
    return v.f;
}
__device__ __forceinline__ unsigned short f2bf(float f) {
    union { float f; unsigned u; } v; v.f = f;
    unsigned u = v.u;
    unsigned r = u + 0x7FFFu + ((u >> 16) & 1u);   // RNE
    return (unsigned short)(r >> 16);
}

// swizzles: rows of 128 bf16 (16 chunks) and 256 bf16 (32 chunks); chunk=16B.
__device__ __forceinline__ int swz(int f, int c) {       // row len 128
    return f * 128 + ((c ^ (f & 7)) << 3);
}
__device__ __forceinline__ int swzA(int f, int c) {      // row len 256
    return f * 256 + ((c ^ (f & 7)) << 3);
}

// two float4 (8 consecutive fp32) -> bf16x8 fragment (packed RNE)
__device__ __forceinline__ bf16x8 cvt8v(float4 x, float4 y) {
    union { bf16x8 v; __hip_bfloat162 h[4]; } R;
    R.h[0] = __float22bfloat162_rn(float2{x.x, x.y});
    R.h[1] = __float22bfloat162_rn(float2{x.z, x.w});
    R.h[2] = __float22bfloat162_rn(float2{y.x, y.y});
    R.h[3] = __float22bfloat162_rn(float2{y.z, y.w});
    return R.v;
}

#define MFMA(a, b, c) __builtin_amdgcn_mfma_f32_16x16x32_bf16((a), (b), (c), 0, 0, 0)

// ---------------------------------------------------------------------------
// Kernel 0: weight prep.
// W1c[j][k] (j in [0,128) out-feature, k in [0,256) concat-input) = W1[k][j]
// W2t[n][k] = W2[k][n]
// ---------------------------------------------------------------------------
__global__ void prep_weights(const float* __restrict__ W1,
                             const float* __restrict__ W2,
                             unsigned short* __restrict__ W1c,
                             unsigned short* __restrict__ W2t) {
    int idx = blockIdx.x * 256 + threadIdx.x;
    if (idx < 128 * 256) {
        int j = idx >> 8, k = idx & 255;
        W1c[idx] = f2bf(W1[k * 128 + j]);
    } else {
        int i2 = idx - 128 * 256;
        if (i2 < 128 * 128) {
            int n = i2 >> 7, k = i2 & 127;
            W2t[i2] = f2bf(W2[k * 128 + n]);
        }
    }
}

// ---------------------------------------------------------------------------
// Fused per-edge kernel. Block = 512 thr = 8 waves = 128 edges.
// Wave = 16 edges (lane ml owns edge wv*16+ml; quad = k/feature part).
// ---------------------------------------------------------------------------
__global__ __launch_bounds__(512, 1) void edge_fused(
    const float* __restrict__ h, const int* __restrict__ src,
    const int* __restrict__ dst, const unsigned short* __restrict__ W1c,
    const unsigned short* __restrict__ W2t, const float* __restrict__ b1,
    const float* __restrict__ b2, const float* __restrict__ W3,
    const float* __restrict__ b3, float* __restrict__ out, int E) {
    __shared__ unsigned short W1s[128 * 256];     // 64KB [out-feat][k=256]
    __shared__ unsigned short W2s[128 * 128];     // 32KB [out-feat][k=128]
    __shared__ unsigned short scr[8 * 16 * 128];  // 32KB: wave x 16 edges x 128 feats
    __shared__ float  cb1[128];
    __shared__ float  cb2[128];
    __shared__ float2 cW3[128];

    int t = threadIdx.x;
    int lane = t & 63;
    int wv = t >> 6;
    int ml = lane & 15, quad = lane >> 4;

    // ---- stage W1s: thread t -> row t>>2 (128 rows), 8 of 32 chunks ----
    {
        int r = t >> 2, q = t & 3;
        const uint4* s = (const uint4*)(W1c + (size_t)r * 256 + q * 64);
#pragma unroll
        for (int i = 0; i < 8; ++i)
            *(uint4*)(W1s + swzA(r, q * 8 + i)) = s[i];
    }
    // ---- stage W2s: thread t -> row t>>2, 4 of 16 chunks ----
    {
        int f = t >> 2, q4 = t & 3;
        const uint4* s = (const uint4*)(W2t + (size_t)f * 128 + q4 * 32);
#pragma unroll
        for (int i = 0; i < 4; ++i)
            *(uint4*)(W2s + swz(f, q4 * 4 + i)) = s[i];
    }
    if (t < 128) {
        cb1[t] = b1[t];
        cb2[t] = b2[t];
        cW3[t] = float2{W3[t * 2 + 0], W3[t * 2 + 1]};
    }

    // ---- batch h gathers (16 x 16B fp32 loads) BEFORE the barrier ----
    int e = blockIdx.x * 128 + wv * 16 + ml;
    int ec = (e < E) ? e : (E - 1);
    int si = src[ec], di = dst[ec];
    const float* hs = h + (size_t)si * 128;
    const float* hd = h + (size_t)di * 128;

    float4 s0a, s0b, s1a, s1b, s2a, s2b, s3a, s3b;
    float4 d0a, d0b, d1a, d1b, d2a, d2b, d3a, d3b;
    {
        int ko = quad * 8;
        s0a = *(const float4*)(hs + ko);       s0b = *(const float4*)(hs + ko + 4);
        s1a = *(const float4*)(hs + 32 + ko);  s1b = *(const float4*)(hs + 36 + ko);
        s2a = *(const float4*)(hs + 64 + ko);  s2b = *(const float4*)(hs + 68 + ko);
        s3a = *(const float4*)(hs + 96 + ko);  s3b = *(const float4*)(hs + 100 + ko);
        d0a = *(const float4*)(hd + ko);       d0b = *(const float4*)(hd + ko + 4);
        d1a = *(const float4*)(hd + 32 + ko);  d1b = *(const float4*)(hd + 36 + ko);
        d2a = *(const float4*)(hd + 64 + ko);  d2b = *(const float4*)(hd + 68 + ko);
        d3a = *(const float4*)(hd + 96 + ko);  d3b = *(const float4*)(hd + 100 + ko);
    }
    // convert: lane (ml,quad) holds h[own edge][k = kk*32 + quad*8 .. +8]
    bf16x8 hsf[4], hdf[4];
    hsf[0] = cvt8v(s0a, s0b); hsf[1] = cvt8v(s1a, s1b);
    hsf[2] = cvt8v(s2a, s2b); hsf[3] = cvt8v(s3a, s3b);
    hdf[0] = cvt8v(d0a, d0b); hdf[1] = cvt8v(d1a, d1b);
    hdf[2] = cvt8v(d2a, d2b); hdf[3] = cvt8v(d3a, d3b);

    __syncthreads();   // LDS ready; only within-wave fences from here on

    unsigned short* scrW = scr + wv * 2048;   // this wave's 16x128 scratch
    bf16x8 afw[4], arv[4];

    // ========== layer 1, FUSED fwd+rev: each W1s fragment read ONCE ========
    {
        f32x4 accf[8] = {}, accr[8] = {};
        __builtin_amdgcn_s_setprio(1);   // T5: favor MFMA-issuing wave
#pragma unroll
        for (int kk = 0; kk < 4; ++kk) {     // k 0..127: fwd<-hs, rev<-hd
#pragma unroll
            for (int ct = 0; ct < 8; ++ct) {
                bf16x8 a = *(const bf16x8*)(W1s + swzA(ct * 16 + ml, kk * 4 + quad));
                accf[ct] = MFMA(a, hsf[kk], accf[ct]);
                accr[ct] = MFMA(a, hdf[kk], accr[ct]);
            }
        }
#pragma unroll
        for (int kk = 4; kk < 8; ++kk) {     // k 128..255: fwd<-hd, rev<-hs
#pragma unroll
            for (int ct = 0; ct < 8; ++ct) {
                bf16x8 a = *(const bf16x8*)(W1s + swzA(ct * 16 + ml, kk * 4 + quad));
                accf[ct] = MFMA(a, hdf[kk - 4], accf[ct]);
                accr[ct] = MFMA(a, hsf[kk - 4], accr[ct]);
            }
        }
        __builtin_amdgcn_s_setprio(0);

        // ---- bounce round 1 (fwd): +b1, relu, pack -> swizzled scratch ----
        // C layout: col = ml (edge), row = feat = ct*16 + quad*4 + reg.
#pragma unroll
        for (int ct = 0; ct < 8; ++ct) {
            int fb = ct * 16 + quad * 4;
            float4 bv = *(const float4*)(cb1 + fb);
            union { uint2 u; __hip_bfloat162 h2[2]; } o;
            o.h2[0] = __float22bfloat162_rn(float2{fmaxf(accf[ct][0] + bv.x, 0.f),
                                                   fmaxf(accf[ct][1] + bv.y, 0.f)});
            o.h2[1] = __float22bfloat162_rn(float2{fmaxf(accf[ct][2] + bv.z, 0.f),
                                                   fmaxf(accf[ct][3] + bv.w, 0.f)});
            int chunk = ct * 2 + (quad >> 1);             // fb>>3
            *(uint2*)(scrW + ml * 128 + ((chunk ^ (ml & 7)) << 3) + ((quad & 1) << 2)) = o.u;
        }
        __threadfence_block();   // within-wave ds_write -> ds_read ordering
#pragma unroll
        for (int kk = 0; kk < 4; ++kk) {
            int chunk = kk * 4 + quad;
            afw[kk] = *(const bf16x8*)(scrW + ml * 128 + ((chunk ^ (ml & 7)) << 3));
        }
        __threadfence_block();   // round-1 reads ordered before round-2 writes

        // ---- bounce round 2 (rev) ----
#pragma unroll
        for (int ct = 0; ct < 8; ++ct) {
            int fb = ct * 16 + quad * 4;
            float4 bv = *(const float4*)(cb1 + fb);
            union { uint2 u; __hip_bfloat162 h2[2]; } o;
            o.h2[0] = __float22bfloat162_rn(float2{fmaxf(accr[ct][0] + bv.x, 0.f),
                                                   fmaxf(accr[ct][1] + bv.y, 0.f)});
            o.h2[1] = __float22bfloat162_rn(float2{fmaxf(accr[ct][2] + bv.z, 0.f),
                                                   fmaxf(accr[ct][3] + bv.w, 0.f)});
            int chunk = ct * 2 + (quad >> 1);
            *(uint2*)(scrW + ml * 128 + ((chunk ^ (ml & 7)) << 3) + ((quad & 1) << 2)) = o.u;
        }
        __threadfence_block();
#pragma unroll
        for (int kk = 0; kk < 4; ++kk) {
            int chunk = kk * 4 + quad;
            arv[kk] = *(const bf16x8*)(scrW + ml * 128 + ((chunk ^ (ml & 7)) << 3));
        }
    }

    // ========== layer 2+3, FUSED fwd+rev: each W2s fragment read ONCE ======
    float p0[4] = {0.f, 0.f, 0.f, 0.f};
    float p1[4] = {0.f, 0.f, 0.f, 0.f};
    {
        f32x4 acc2f[8] = {}, acc2r[8] = {};
        __builtin_amdgcn_s_setprio(1);
#pragma unroll
        for (int kk = 0; kk < 4; ++kk) {
#pragma unroll
            for (int ct = 0; ct < 8; ++ct) {
                bf16x8 b = *(const bf16x8*)(W2s + swz(ct * 16 + ml, kk * 4 + quad));
                acc2f[ct] = MFMA(afw[kk], b, acc2f[ct]);
                acc2r[ct] = MFMA(arv[kk], b, acc2r[ct]);
            }
        }
        __builtin_amdgcn_s_setprio(0);
        // epilogue: +b2, relu, dot W3 columns; fwd+rev folded into p0/p1
#pragma unroll
        for (int ct = 0; ct < 8; ++ct) {
            int c = ct * 16 + ml;
            float2 w3 = cW3[c];
            float bc = cb2[c];
#pragma unroll
            for (int reg = 0; reg < 4; ++reg) {
                float hf = fmaxf(acc2f[ct][reg] + bc, 0.f);
                float hr = fmaxf(acc2r[ct][reg] + bc, 0.f);
                p0[reg] += (hf + hr) * w3.x;
                p1[reg] += (hf + hr) * w3.y;
            }
        }
    }

    // butterfly over the 16 feature lanes
#pragma unroll
    for (int m = 1; m < 16; m <<= 1) {
#pragma unroll
        for (int reg = 0; reg < 4; ++reg) {
            p0[reg] += __shfl_xor(p0[reg], m);
            p1[reg] += __shfl_xor(p1[reg], m);
        }
    }

    // lane ml==0 writes component 0, ml==1 writes component 1
    if (ml < 2) {
        float bb = 2.f * b3[ml];
#pragma unroll
        for (int reg = 0; reg < 4; ++reg) {
            int ee = blockIdx.x * 128 + wv * 16 + quad * 4 + reg;
            if (ee < E) {
                float v = (ml == 0) ? p0[reg] : p1[reg];
                out[(size_t)ee * 2 + ml] = v + bb;
            }
        }
    }
}

// ---------------------------------------------------------------------------
extern "C" void kernel_launch(void* const* d_in, const int* in_sizes, int n_in,
                              void* d_out, int out_size, void* d_ws, size_t ws_size,
                              hipStream_t stream) {
    (void)n_in; (void)out_size; (void)ws_size;
    const float* h  = (const float*)d_in[0];
    const int*   sr = (const int*)d_in[1];
    const int*   ds = (const int*)d_in[2];
    const float* W1 = (const float*)d_in[3];
    const float* b1 = (const float*)d_in[4];
    const float* W2 = (const float*)d_in[5];
    const float* b2 = (const float*)d_in[6];
    const float* W3 = (const float*)d_in[7];
    const float* b3 = (const float*)d_in[8];
    float* out = (float*)d_out;

    int E = in_sizes[1];

    unsigned short* W1c = (unsigned short*)d_ws;          // 128*256
    unsigned short* W2t = W1c + 128 * 256;                // 128*128

    prep_weights<<<(128 * 256 + 128 * 128 + 255) / 256, 256, 0, stream>>>(W1, W2, W1c, W2t);

    int etiles = (E + 127) / 128;
    edge_fused<<<etiles, 512, 0, stream>>>(h, sr, ds, W1c, W2t, b1, b2, W3, b3, out, E);
}

// Round 13
// 222.723 us; speedup vs baseline: 1.0633x; 1.0246x over previous
//
#include <hip/hip_runtime.h>
#include <hip/hip_bf16.h>
#include <stdint.h>

// ---------------------------------------------------------------------------
// BondPoolingLayer: out[e] = MLP(cat(h[src],h[dst])) + MLP(cat(h[dst],h[src]))
// MLP: 256 ->(W1,b1,relu) 128 ->(W2,b2,relu) 128 ->(W3,b3) 2
//
// R18 = R17 fused kernel at 12 waves/CU (768-thr block, the untested point
//       that evades the R15<->R16 occupancy/register binary).
//  - R15<->R16 proved: 2 blocks/CU => <=128 regs => gather window dies.
//    But ONE 768-thr block (12 waves, 3 waves/SIMD) allows 512/3 = 170
//    regs/wave; R17's measured live-set is 88 VGPR + 64 AGPR = 152 <= 170.
//    Full gather window AND +50% waves/CU for the gather-bound phase.
//  - LDS: W1s 64K + W2s 32K + scr 12x4K + consts ~= 146KB <= 160KB.
//  - Staging split: t<512 stage W1s; t>=512 stage W2s (concurrent).
//  - Cap (768,3)=170 is 18 regs ABOVE measured need — not the R6/R8
//    cap-on-live-set trap.
//  - Falsifier: dur >= 108us or spill signature -> R17 is the floor.
// ---------------------------------------------------------------------------

typedef __attribute__((ext_vector_type(8))) short bf16x8;
typedef __attribute__((ext_vector_type(4))) float f32x4;

__device__ __forceinline__ float bf2f(unsigned u16) {
    union { unsigned u; float f; } v; v.u = u16 << 16;
    return v.f;
}
__device__ __forceinline__ unsigned short f2bf(float f) {
    union { float f; unsigned u; } v; v.f = f;
    unsigned u = v.u;
    unsigned r = u + 0x7FFFu + ((u >> 16) & 1u);   // RNE
    return (unsigned short)(r >> 16);
}

// swizzles: rows of 128 bf16 (16 chunks) and 256 bf16 (32 chunks); chunk=16B.
__device__ __forceinline__ int swz(int f, int c) {       // row len 128
    return f * 128 + ((c ^ (f & 7)) << 3);
}
__device__ __forceinline__ int swzA(int f, int c) {      // row len 256
    return f * 256 + ((c ^ (f & 7)) << 3);
}

// two float4 (8 consecutive fp32) -> bf16x8 fragment (packed RNE)
__device__ __forceinline__ bf16x8 cvt8v(float4 x, float4 y) {
    union { bf16x8 v; __hip_bfloat162 h[4]; } R;
    R.h[0] = __float22bfloat162_rn(float2{x.x, x.y});
    R.h[1] = __float22bfloat162_rn(float2{x.z, x.w});
    R.h[2] = __float22bfloat162_rn(float2{y.x, y.y});
    R.h[3] = __float22bfloat162_rn(float2{y.z, y.w});
    return R.v;
}

#define MFMA(a, b, c) __builtin_amdgcn_mfma_f32_16x16x32_bf16((a), (b), (c), 0, 0, 0)

// ---------------------------------------------------------------------------
// Kernel 0: weight prep.
// W1c[j][k] (j in [0,128) out-feature, k in [0,256) concat-input) = W1[k][j]
// W2t[n][k] = W2[k][n]
// ---------------------------------------------------------------------------
__global__ void prep_weights(const float* __restrict__ W1,
                             const float* __restrict__ W2,
                             unsigned short* __restrict__ W1c,
                             unsigned short* __restrict__ W2t) {
    int idx = blockIdx.x * 256 + threadIdx.x;
    if (idx < 128 * 256) {
        int j = idx >> 8, k = idx & 255;
        W1c[idx] = f2bf(W1[k * 128 + j]);
    } else {
        int i2 = idx - 128 * 256;
        if (i2 < 128 * 128) {
            int n = i2 >> 7, k = i2 & 127;
            W2t[i2] = f2bf(W2[k * 128 + n]);
        }
    }
}

// ---------------------------------------------------------------------------
// Fused per-edge kernel. Block = 768 thr = 12 waves = 192 edges.
// Wave = 16 edges (lane ml owns edge wv*16+ml; quad = k/feature part).
// ---------------------------------------------------------------------------
__global__ __launch_bounds__(768, 3) void edge_fused(
    const float* __restrict__ h, const int* __restrict__ src,
    const int* __restrict__ dst, const unsigned short* __restrict__ W1c,
    const unsigned short* __restrict__ W2t, const float* __restrict__ b1,
    const float* __restrict__ b2, const float* __restrict__ W3,
    const float* __restrict__ b3, float* __restrict__ out, int E) {
    __shared__ unsigned short W1s[128 * 256];      // 64KB [out-feat][k=256]
    __shared__ unsigned short W2s[128 * 128];      // 32KB [out-feat][k=128]
    __shared__ unsigned short scr[12 * 16 * 128];  // 48KB: wave x 16 edges x 128
    __shared__ float  cb1[128];
    __shared__ float  cb2[128];
    __shared__ float2 cW3[128];

    int t = threadIdx.x;
    int lane = t & 63;
    int wv = t >> 6;                 // 0..11
    int ml = lane & 15, quad = lane >> 4;

    // ---- staging split: t<512 -> W1s (8 of 32 chunks per thread);
    //      t>=512 (256 thr) -> W2s (8 of 16 chunks per thread, 2 thr/row) ----
    if (t < 512) {
        int r = t >> 2, q = t & 3;
        const uint4* s = (const uint4*)(W1c + (size_t)r * 256 + q * 64);
#pragma unroll
        for (int i = 0; i < 8; ++i)
            *(uint4*)(W1s + swzA(r, q * 8 + i)) = s[i];
    } else {
        int t2 = t - 512;                 // 0..255
        int f = t2 >> 1, q8 = t2 & 1;     // row f, half q8
        const uint4* s = (const uint4*)(W2t + (size_t)f * 128 + q8 * 64);
#pragma unroll
        for (int i = 0; i < 8; ++i)
            *(uint4*)(W2s + swz(f, q8 * 8 + i)) = s[i];
    }
    if (t < 128) {
        cb1[t] = b1[t];
        cb2[t] = b2[t];
        cW3[t] = float2{W3[t * 2 + 0], W3[t * 2 + 1]};
    }

    // ---- batch h gathers (16 x 16B fp32 loads) BEFORE the barrier ----
    int e = blockIdx.x * 192 + wv * 16 + ml;
    int ec = (e < E) ? e : (E - 1);
    int si = src[ec], di = dst[ec];
    const float* hs = h + (size_t)si * 128;
    const float* hd = h + (size_t)di * 128;

    float4 s0a, s0b, s1a, s1b, s2a, s2b, s3a, s3b;
    float4 d0a, d0b, d1a, d1b, d2a, d2b, d3a, d3b;
    {
        int ko = quad * 8;
        s0a = *(const float4*)(hs + ko);       s0b = *(const float4*)(hs + ko + 4);
        s1a = *(const float4*)(hs + 32 + ko);  s1b = *(const float4*)(hs + 36 + ko);
        s2a = *(const float4*)(hs + 64 + ko);  s2b = *(const float4*)(hs + 68 + ko);
        s3a = *(const float4*)(hs + 96 + ko);  s3b = *(const float4*)(hs + 100 + ko);
        d0a = *(const float4*)(hd + ko);       d0b = *(const float4*)(hd + ko + 4);
        d1a = *(const float4*)(hd + 32 + ko);  d1b = *(const float4*)(hd + 36 + ko);
        d2a = *(const float4*)(hd + 64 + ko);  d2b = *(const float4*)(hd + 68 + ko);
        d3a = *(const float4*)(hd + 96 + ko);  d3b = *(const float4*)(hd + 100 + ko);
    }
    // convert: lane (ml,quad) holds h[own edge][k = kk*32 + quad*8 .. +8]
    bf16x8 hsf[4], hdf[4];
    hsf[0] = cvt8v(s0a, s0b); hsf[1] = cvt8v(s1a, s1b);
    hsf[2] = cvt8v(s2a, s2b); hsf[3] = cvt8v(s3a, s3b);
    hdf[0] = cvt8v(d0a, d0b); hdf[1] = cvt8v(d1a, d1b);
    hdf[2] = cvt8v(d2a, d2b); hdf[3] = cvt8v(d3a, d3b);

    __syncthreads();   // LDS ready; only within-wave fences from here on

    unsigned short* scrW = scr + wv * 2048;   // this wave's 16x128 scratch
    bf16x8 afw[4], arv[4];

    // ========== layer 1, FUSED fwd+rev: each W1s fragment read ONCE ========
    {
        f32x4 accf[8] = {}, accr[8] = {};
        __builtin_amdgcn_s_setprio(1);
#pragma unroll
        for (int kk = 0; kk < 4; ++kk) {     // k 0..127: fwd<-hs, rev<-hd
#pragma unroll
            for (int ct = 0; ct < 8; ++ct) {
                bf16x8 a = *(const bf16x8*)(W1s + swzA(ct * 16 + ml, kk * 4 + quad));
                accf[ct] = MFMA(a, hsf[kk], accf[ct]);
                accr[ct] = MFMA(a, hdf[kk], accr[ct]);
            }
        }
#pragma unroll
        for (int kk = 4; kk < 8; ++kk) {     // k 128..255: fwd<-hd, rev<-hs
#pragma unroll
            for (int ct = 0; ct < 8; ++ct) {
                bf16x8 a = *(const bf16x8*)(W1s + swzA(ct * 16 + ml, kk * 4 + quad));
                accf[ct] = MFMA(a, hdf[kk - 4], accf[ct]);
                accr[ct] = MFMA(a, hsf[kk - 4], accr[ct]);
            }
        }
        __builtin_amdgcn_s_setprio(0);

        // ---- bounce round 1 (fwd): +b1, relu, pack -> swizzled scratch ----
        // C layout: col = ml (edge), row = feat = ct*16 + quad*4 + reg.
#pragma unroll
        for (int ct = 0; ct < 8; ++ct) {
            int fb = ct * 16 + quad * 4;
            float4 bv = *(const float4*)(cb1 + fb);
            union { uint2 u; __hip_bfloat162 h2[2]; } o;
            o.h2[0] = __float22bfloat162_rn(float2{fmaxf(accf[ct][0] + bv.x, 0.f),
                                                   fmaxf(accf[ct][1] + bv.y, 0.f)});
            o.h2[1] = __float22bfloat162_rn(float2{fmaxf(accf[ct][2] + bv.z, 0.f),
                                                   fmaxf(accf[ct][3] + bv.w, 0.f)});
            int chunk = ct * 2 + (quad >> 1);             // fb>>3
            *(uint2*)(scrW + ml * 128 + ((chunk ^ (ml & 7)) << 3) + ((quad & 1) << 2)) = o.u;
        }
        __threadfence_block();   // within-wave ds_write -> ds_read ordering
#pragma unroll
        for (int kk = 0; kk < 4; ++kk) {
            int chunk = kk * 4 + quad;
            afw[kk] = *(const bf16x8*)(scrW + ml * 128 + ((chunk ^ (ml & 7)) << 3));
        }
        __threadfence_block();   // round-1 reads ordered before round-2 writes

        // ---- bounce round 2 (rev) ----
#pragma unroll
        for (int ct = 0; ct < 8; ++ct) {
            int fb = ct * 16 + quad * 4;
            float4 bv = *(const float4*)(cb1 + fb);
            union { uint2 u; __hip_bfloat162 h2[2]; } o;
            o.h2[0] = __float22bfloat162_rn(float2{fmaxf(accr[ct][0] + bv.x, 0.f),
                                                   fmaxf(accr[ct][1] + bv.y, 0.f)});
            o.h2[1] = __float22bfloat162_rn(float2{fmaxf(accr[ct][2] + bv.z, 0.f),
                                                   fmaxf(accr[ct][3] + bv.w, 0.f)});
            int chunk = ct * 2 + (quad >> 1);
            *(uint2*)(scrW + ml * 128 + ((chunk ^ (ml & 7)) << 3) + ((quad & 1) << 2)) = o.u;
        }
        __threadfence_block();
#pragma unroll
        for (int kk = 0; kk < 4; ++kk) {
            int chunk = kk * 4 + quad;
            arv[kk] = *(const bf16x8*)(scrW + ml * 128 + ((chunk ^ (ml & 7)) << 3));
        }
    }

    // ========== layer 2+3, FUSED fwd+rev: each W2s fragment read ONCE ======
    float p0[4] = {0.f, 0.f, 0.f, 0.f};
    float p1[4] = {0.f, 0.f, 0.f, 0.f};
    {
        f32x4 acc2f[8] = {}, acc2r[8] = {};
        __builtin_amdgcn_s_setprio(1);
#pragma unroll
        for (int kk = 0; kk < 4; ++kk) {
#pragma unroll
            for (int ct = 0; ct < 8; ++ct) {
                bf16x8 b = *(const bf16x8*)(W2s + swz(ct * 16 + ml, kk * 4 + quad));
                acc2f[ct] = MFMA(afw[kk], b, acc2f[ct]);
                acc2r[ct] = MFMA(arv[kk], b, acc2r[ct]);
            }
        }
        __builtin_amdgcn_s_setprio(0);
        // epilogue: +b2, relu, dot W3 columns; fwd+rev folded into p0/p1
#pragma unroll
        for (int ct = 0; ct < 8; ++ct) {
            int c = ct * 16 + ml;
            float2 w3 = cW3[c];
            float bc = cb2[c];
#pragma unroll
            for (int reg = 0; reg < 4; ++reg) {
                float hf = fmaxf(acc2f[ct][reg] + bc, 0.f);
                float hr = fmaxf(acc2r[ct][reg] + bc, 0.f);
                p0[reg] += (hf + hr) * w3.x;
                p1[reg] += (hf + hr) * w3.y;
            }
        }
    }

    // butterfly over the 16 feature lanes
#pragma unroll
    for (int m = 1; m < 16; m <<= 1) {
#pragma unroll
        for (int reg = 0; reg < 4; ++reg) {
            p0[reg] += __shfl_xor(p0[reg], m);
            p1[reg] += __shfl_xor(p1[reg], m);
        }
    }

    // lane ml==0 writes component 0, ml==1 writes component 1
    if (ml < 2) {
        float bb = 2.f * b3[ml];
#pragma unroll
        for (int reg = 0; reg < 4; ++reg) {
            int ee = blockIdx.x * 192 + wv * 16 + quad * 4 + reg;
            if (ee < E) {
                float v = (ml == 0) ? p0[reg] : p1[reg];
                out[(size_t)ee * 2 + ml] = v + bb;
            }
        }
    }
}

// ---------------------------------------------------------------------------
extern "C" void kernel_launch(void* const* d_in, const int* in_sizes, int n_in,
                              void* d_out, int out_size, void* d_ws, size_t ws_size,
                              hipStream_t stream) {
    (void)n_in; (void)out_size; (void)ws_size;
    const float* h  = (const float*)d_in[0];
    const int*   sr = (const int*)d_in[1];
    const int*   ds = (const int*)d_in[2];
    const float* W1 = (const float*)d_in[3];
    const float* b1 = (const float*)d_in[4];
    const float* W2 = (const float*)d_in[5];
    const float* b2 = (const float*)d_in[6];
    const float* W3 = (const float*)d_in[7];
    const float* b3 = (const float*)d_in[8];
    float* out = (float*)d_out;

    int E = in_sizes[1];

    unsigned short* W1c = (unsigned short*)d_ws;          // 128*256
    unsigned short* W2t = W1c + 128 * 256;                // 128*128

    prep_weights<<<(128 * 256 + 128 * 128 + 255) / 256, 256, 0, stream>>>(W1, W2, W1c, W2t);

    int etiles = (E + 191) / 192;
    edge_fused<<<etiles, 768, 0, stream>>>(h, sr, ds, W1c, W2t, b1, b2, W3, b3, out, E);
}